// Round 24
// baseline (105.450 us; speedup 1.0000x reference)
//
#include <hip/hip_runtime.h>
#include <hip/hip_bf16.h>
#include <math.h>

// OptimizeSNR R24: Toeplitz-swap MFMA + rolling LDS ring (each x element
// loaded from global EXACTLY ONCE -> per-output vmem bytes 12 -> 8).
//   Ring: 128 x 16B granules per wave (1024 bf16 positions); position p lives
//   at granule (p/8) & 127. Per iter (2 tiles = 512 outputs): 10 ds_read frags,
//   THEN 1 ds_write of 512 new positions (clobbers only already-read slots;
//   same-wave DS is in-order), 2 loads (next write), 20 MFMA, 8 stores.
//   Zero barriers; counted vmcnt; wave-autonomous.
constexpr int Bc = 8, Cc = 128, Lc = 32768, Kc = 129;

constexpr int T     = 16;              // tiles per wave-segment
constexpr int NITER = T / 2;           // 8 iterations (2 tiles each)
constexpr int NSEG  = Lc / (256 * T);  // 8 segments per row
constexpr int WPB   = 4;
constexpr int THREADS = 64 * WPB;      // 256

typedef __attribute__((ext_vector_type(8))) short short8;
typedef __attribute__((ext_vector_type(4))) float floatx4;

#define WAITVM(N) do { asm volatile("s_waitcnt vmcnt(" #N ")" ::: "memory"); \
                       __builtin_amdgcn_sched_barrier(0); } while (0)

__device__ __forceinline__ unsigned short f2bf(float f) {
    return __builtin_bit_cast(unsigned short, __float2bfloat16(f));
}

__device__ __forceinline__ short8 cvt8(const float4& a, const float4& b) {
    __hip_bfloat162 p0 = __float22bfloat162_rn(make_float2(a.x, a.y));
    __hip_bfloat162 p1 = __float22bfloat162_rn(make_float2(a.z, a.w));
    __hip_bfloat162 p2 = __float22bfloat162_rn(make_float2(b.x, b.y));
    __hip_bfloat162 p3 = __float22bfloat162_rn(make_float2(b.z, b.w));
    ushort2 u0, u1, u2, u3;
    __builtin_memcpy(&u0, &p0, 4);
    __builtin_memcpy(&u1, &p1, 4);
    __builtin_memcpy(&u2, &p2, 4);
    __builtin_memcpy(&u3, &p3, 4);
    short8 r;
    r[0] = (short)u0.x; r[1] = (short)u0.y;
    r[2] = (short)u1.x; r[3] = (short)u1.y;
    r[4] = (short)u2.x; r[5] = (short)u2.y;
    r[6] = (short)u3.x; r[7] = (short)u3.y;
    return r;
}

// Per-channel complex scale: sc = nm*cos(atan(a)), ss = nm*sin(atan(a))
__global__ void scale_kernel(const float* __restrict__ wm,
                             const float* __restrict__ wa,
                             float* __restrict__ ws, int C, float batchf) {
    int c = threadIdx.x;
    if (c >= C) return;
    float m = -1e30f;
    for (int i = 0; i < C; ++i) m = fmaxf(m, wm[i]);
    float s = 0.f;
    for (int i = 0; i < C; ++i) s += expf(wm[i] - m);
    float nm = batchf * expf(wm[c] - m) / s;
    float a = wa[c];
    float inv = rsqrtf(1.f + a * a);
    ws[2 * c]     = nm * inv;       // sc
    ws[2 * c + 1] = nm * a * inv;   // ss
}

__global__ __launch_bounds__(THREADS, 4)
void mf_kernel(const float* __restrict__ x,
               const float* __restrict__ kr,
               const float* __restrict__ ki,
               const float* __restrict__ sc_ss,
               float* __restrict__ out, int interleaved) {
    __shared__ __align__(16) unsigned short lb[WPB][1024];   // 8 KB: rings

    const int seg = blockIdx.x;            // 8 segments
    const int rg  = blockIdx.y;            // 256 row groups (4 rows)
    const int tid = threadIdx.x;
    const int lane= tid & 63;
    const int wv  = tid >> 6;
    const int fh  = lane >> 4;             // 0..3
    const int fn  = lane & 15;             // 0..15
    const int v   = 2 * fn + fh;           // fragment granule offset base

    const int row = rg * WPB + wv;         // 0..1023
    const int I0  = seg * NITER;           // absolute iter index base (0..63)

    // ---- B fragments (k-Toeplitz): B_d[kl][n] = k[32d+kl-n]; lane: n=fn, kl=8*fh+e
    short8 br[5], bi[5];
    #pragma unroll
    for (int d = 0; d < 5; ++d) {
        #pragma unroll
        for (int e = 0; e < 8; ++e) {
            int idx = 32 * d + 8 * fh + e - fn;
            bool ok = (idx >= 0) && (idx < Kc);
            br[d][e] = (short)f2bf(ok ? kr[idx] : 0.f);
            bi[d][e] = (short)f2bf(ok ? ki[idx] : 0.f);
        }
    }

    const int ch = row & (Cc - 1);
    const float scv = sc_ss[2 * ch];
    const float ssv = sc_ss[2 * ch + 1];

    const float* __restrict__ xrow = x + (size_t)row * Lc;
    unsigned short* ring = &lb[wv][0];

    float4 F0, F1;
    // loads for the write performed at iter I+? : positions [512*Iw+960 + 8L)
    auto ISSUE = [&](int Iw) {
        int g = 512 * Iw + 960 + 8 * lane;
        g = min(max(g, 0), Lc - 8);
        F0 = *reinterpret_cast<const float4*>(xrow + g);
        F1 = *reinterpret_cast<const float4*>(xrow + g + 4);
    };

    // ---- prologue: fill entire ring = positions [512*I0-64, 512*I0+960) ----
    {
        int gA = 512 * I0 - 64 + 8 * lane;
        int gB = 512 * I0 + 448 + 8 * lane;
        gA = min(max(gA, 0), Lc - 8);
        gB = min(max(gB, 0), Lc - 8);
        float4 a0 = *reinterpret_cast<const float4*>(xrow + gA);
        float4 a1 = *reinterpret_cast<const float4*>(xrow + gA + 4);
        float4 b0 = *reinterpret_cast<const float4*>(xrow + gB);
        float4 b1 = *reinterpret_cast<const float4*>(xrow + gB + 4);
        WAITVM(0);
        short8 ha = cvt8(a0, a1);
        short8 hb = cvt8(b0, b1);
        *reinterpret_cast<short8*>(&ring[8 * ((64 * I0 - 8 + lane) & 127)]) = ha;
        *reinterpret_cast<short8*>(&ring[8 * ((64 * I0 + 56 + lane) & 127)]) = hb;
        ISSUE(I0);   // feeds the write at local iter 0
    }

    #pragma unroll
    for (int i = 0; i < NITER; ++i) {
        const int I = I0 + i;              // absolute iter (0..63)

        // ---- 10 fragment reads (tiles 2I and 2I+1) from the ring ----
        short8 a0[5], a1[5];
        #pragma unroll
        for (int d = 0; d < 5; ++d) {
            const int s0 = (64 * I - 8 + v + 4 * d) & 127;
            const int s1 = (64 * I + 24 + v + 4 * d) & 127;
            a0[d] = *reinterpret_cast<const short8*>(&ring[8 * s0]);
            a1[d] = *reinterpret_cast<const short8*>(&ring[8 * s1]);
        }
        // edge zeroing (wave-uniform branches)
        if (I == 0) {
            #pragma unroll
            for (int d = 0; d < 5; ++d)
                if (v + 4 * d < 8) a0[d] = short8{0,0,0,0,0,0,0,0};
        }
        if (I == 63) {
            #pragma unroll
            for (int d = 0; d < 5; ++d)
                if (v + 4 * d >= 40) a1[d] = short8{0,0,0,0,0,0,0,0};
        }
        __builtin_amdgcn_sched_barrier(0);  // reads stay BEFORE the ring write

        // ---- ring write of the next 512 positions (slots just read-retired) ----
        if (i < NITER - 1) {
            if (i == 0) WAITVM(0); else WAITVM(8);
            short8 h = cvt8(F0, F1);
            *reinterpret_cast<short8*>(&ring[8 * ((64 * I + 120 + lane) & 127)]) = h;
            if (i < NITER - 2) ISSUE(I + 1);
        }

        // ---- 20 MFMA: two 16x16 tiles ----
        floatx4 c0r = {0.f,0.f,0.f,0.f}, c0i = {0.f,0.f,0.f,0.f};
        floatx4 c1r = {0.f,0.f,0.f,0.f}, c1i = {0.f,0.f,0.f,0.f};
        #pragma unroll
        for (int d = 0; d < 5; ++d) {
            c0r = __builtin_amdgcn_mfma_f32_16x16x32_bf16(a0[d], br[d], c0r, 0, 0, 0);
            c0i = __builtin_amdgcn_mfma_f32_16x16x32_bf16(a0[d], bi[d], c0i, 0, 0, 0);
            c1r = __builtin_amdgcn_mfma_f32_16x16x32_bf16(a1[d], br[d], c1r, 0, 0, 0);
            c1i = __builtin_amdgcn_mfma_f32_16x16x32_bf16(a1[d], bi[d], c1i, 0, 0, 0);
        }

        // ---- stores: D[m=4*fh+r][n=fn]; tile0 at 512I, tile1 at 512I+256 ----
        if (!interleaved) {
            float* op = out + (size_t)row * Lc + 512 * I + 64 * fh + fn;
            #pragma unroll
            for (int r = 0; r < 4; ++r) {
                op[16 * r]       = scv * c0r[r] - ssv * c0i[r];
                op[16 * r + 256] = scv * c1r[r] - ssv * c1i[r];
            }
        } else {
            float2* op = reinterpret_cast<float2*>(out) +
                         ((size_t)row * Lc + 512 * I + 64 * fh + fn);
            #pragma unroll
            for (int r = 0; r < 4; ++r) {
                op[16 * r]       = make_float2(scv * c0r[r] - ssv * c0i[r],
                                               -scv * c0i[r] - ssv * c0r[r]);
                op[16 * r + 256] = make_float2(scv * c1r[r] - ssv * c1i[r],
                                               -scv * c1i[r] - ssv * c1r[r]);
            }
        }
    }
}

extern "C" void kernel_launch(void* const* d_in, const int* in_sizes, int n_in,
                              void* d_out, int out_size, void* d_ws, size_t ws_size,
                              hipStream_t stream) {
    const float* x  = (const float*)d_in[0];
    const float* wm = (const float*)d_in[1];
    const float* wa = (const float*)d_in[2];
    const float* kr = (const float*)d_in[3];
    const float* ki = (const float*)d_in[4];
    float* out = (float*)d_out;
    float* ws  = (float*)d_ws;

    const int C = in_sizes[1];  // 128
    const long long N = (long long)Bc * Cc * Lc;
    const int interleaved = (out_size == 2 * N) ? 1 : 0;

    hipLaunchKernelGGL(scale_kernel, dim3(1), dim3(C), 0, stream,
                       wm, wa, ws, C, (float)Bc);

    dim3 grid(NSEG, (Bc * Cc) / WPB);   // 8 x 256 = 2048 blocks
    hipLaunchKernelGGL(mf_kernel, grid, dim3(THREADS), 0, stream,
                       x, kr, ki, ws, out, interleaved);
}